// Round 9
// baseline (214.063 us; speedup 1.0000x reference)
//
#include <hip/hip_runtime.h>
#include <hip/hip_bf16.h>
#include <hip/hip_fp16.h>

#define NN 100000
#define NE 3200000
#define IN_F 128
#define HID 32

#define BNODES 98       // nodes per bucket (dst / 98)
#define NB 1021         // ceil(NN/BNODES) -> 3.99 blocks/CU on 256 CUs
#define NBP1 (NB + 1)
#define PBLK 768        // partition blocks -> 3.0 blocks/CU
#define EPB 4168        // ceil(NE/PBLK) edges per partition block (even)
#define SSPAN 3584      // per-bucket span bound: mean 3136 + 8 sigma (56); = 7*512

typedef __hip_bfloat16 bf16;
typedef __attribute__((ext_vector_type(8))) short s16x8;   // 8 bf16 (4 VGPRs)
typedef __attribute__((ext_vector_type(4))) float f32x4;   // MFMA C/D

// ---------------- partition: LDS counting sort, ALL global writes dense ----------------
__global__ __launch_bounds__(512) void k_part(const int* __restrict__ ei,
                                              const float* __restrict__ ew,
                                              int* __restrict__ offs,
                                              uint2* __restrict__ raw) {
    __shared__ int hist[NB];
    __shared__ int start[NB];
    __shared__ int wtot8[8];
    __shared__ __align__(16) uint2 sp[EPB];   // 33.3 KB

    int t = threadIdx.x;
    int blk = blockIdx.x;
    for (int b = t; b < NB; b += 512) hist[b] = 0;
    __syncthreads();

    unsigned pk[10]; unsigned wb[10]; int bkt[10];
    int base_e = blk * EPB;
#pragma unroll
    for (int j = 0; j < 5; j++) {
        int p = j * 512 + t;               // pair index within block
        int e = base_e + 2 * p;
        bool v = (p < (EPB / 2)) && (e < NE);
        if (v) {
            int2   s2 = *(const int2*)(ei + e);
            int2   d2 = *(const int2*)(ei + NE + e);
            float2 w2 = *(const float2*)(ew + e);
            int bk0 = d2.x / BNODES;           // magic-mul by compiler
            bkt[2 * j]     = bk0;
            pk[2 * j]      = (unsigned)s2.x | ((unsigned)(d2.x - bk0 * BNODES) << 20);
            wb[2 * j]      = __float_as_uint(w2.x);
            int bk1 = d2.y / BNODES;
            bkt[2 * j + 1] = bk1;
            pk[2 * j + 1]  = (unsigned)s2.y | ((unsigned)(d2.y - bk1 * BNODES) << 20);
            wb[2 * j + 1]  = __float_as_uint(w2.y);
        } else { bkt[2 * j] = -1; bkt[2 * j + 1] = -1; }
    }
#pragma unroll
    for (int j = 0; j < 10; j++)
        if (bkt[j] >= 0) atomicAdd(&hist[bkt[j]], 1);
    __syncthreads();

    // exclusive scan over 1021 bins (2 per thread, shuffle-based)
    int e0 = 2 * t, e1 = 2 * t + 1;
    int h0 = (e0 < NB) ? hist[e0] : 0;
    int h1 = (e1 < NB) ? hist[e1] : 0;
    int psum = h0 + h1;
    int lane = t & 63;
    int incl = psum;
#pragma unroll
    for (int off = 1; off < 64; off <<= 1) {
        int up = __shfl_up(incl, off, 64);
        if (lane >= off) incl += up;
    }
    int wid = t >> 6;
    if (lane == 63) wtot8[wid] = incl;
    __syncthreads();
    int woff = 0;
    for (int wj = 0; wj < wid; wj++) woff += wtot8[wj];
    int exc = woff + incl - psum;
    if (e0 < NB) start[e0] = exc;
    if (e1 < NB) start[e1] = exc + h0;
    __syncthreads();

    int total = start[NB - 1] + hist[NB - 1];
    int* orow = offs + (size_t)blk * NBP1;
    for (int b = t; b < NB; b += 512) orow[b] = start[b];
    if (t == 0) orow[NB] = total;
    __syncthreads();   // orow reads of start[] complete before cursor mutation

    // LDS counting scatter (start[] becomes cursor)
#pragma unroll
    for (int j = 0; j < 10; j++) {
        if (bkt[j] >= 0) {
            int pos = atomicAdd(&start[bkt[j]], 1);
            sp[pos] = make_uint2(pk[j], wb[j]);
        }
    }
    __syncthreads();

    // dense, coalesced 16B copy to block-private region (written exactly once)
    uint2* r = raw + (size_t)blk * EPB;    // EPB*8 bytes, 16B-aligned per block
    int tot2 = total >> 1;
    const uint4* sp4 = (const uint4*)sp;
    uint4* r4 = (uint4*)r;
    for (int i = t; i < tot2; i += 512) r4[i] = sp4[i];
    if (t == 0 && (total & 1)) r[total - 1] = sp[total - 1];
}

// ---------------- per-bucket weighted degree -> dinv (LDS atomics, dense writes) ----------
// Reads offs COLUMNS directly (adjacent cols b, b+1 share a cache line) — no transpose.
__global__ __launch_bounds__(512) void k_deg(const int* __restrict__ offs,
                                             const uint2* __restrict__ raw,
                                             float* __restrict__ dinv) {
    __shared__ unsigned short runid[SSPAN];   //  7.0 KB
    __shared__ int P[PBLK + 1];               //  3.1 KB
    __shared__ int basearr[PBLK];             //  3.1 KB  (= O0[r] - P[r])
    __shared__ float wsum[BNODES];
    __shared__ int wt8[8];

    int t = threadIdx.x;
    int b = blockIdx.x;
    if (t < BNODES) wsum[t] = 0.f;

    int e0 = 2 * t, e1 = 2 * t + 1;
    int l0 = 0, l1 = 0, o0v = 0, o1v = 0;
    if (e0 < PBLK) {
        o0v = offs[(size_t)e0 * NBP1 + b];
        l0  = offs[(size_t)e0 * NBP1 + b + 1] - o0v;
    }
    if (e1 < PBLK) {
        o1v = offs[(size_t)e1 * NBP1 + b];
        l1  = offs[(size_t)e1 * NBP1 + b + 1] - o1v;
    }
    int psum = l0 + l1;
    int lane = t & 63;
    int incl = psum;
#pragma unroll
    for (int off = 1; off < 64; off <<= 1) {
        int up = __shfl_up(incl, off, 64);
        if (lane >= off) incl += up;
    }
    int wid = t >> 6;
    if (lane == 63) wt8[wid] = incl;
    __syncthreads();          // covers wsum init
    int woff = 0;
    for (int wj = 0; wj < wid; wj++) woff += wt8[wj];
    int exc = woff + incl - psum;
    if (e0 < PBLK) { P[e0] = exc;      basearr[e0] = o0v - exc; }
    if (e1 < PBLK) { P[e1] = exc + l0; basearr[e1] = o1v - (exc + l0); }
    if (t == 0) {
        int s = 0;
#pragma unroll
        for (int j = 0; j < 8; j++) s += wt8[j];
        P[PBLK] = s;
    }
    __syncthreads();

    int total = min(P[PBLK], SSPAN);

    for (int r = t; r < PBLK; r += 512) {
        int p0 = P[r], p1 = min(P[r + 1], SSPAN);
        for (int i = p0; i < p1; i++) runid[i] = (unsigned short)r;
    }
    __syncthreads();

#pragma unroll
    for (int k = 0; k < 7; k++) {
        int d = t + k * 512;
        if (d < total) {
            int r = runid[d];
            uint2 rec = raw[(size_t)r * EPB + (basearr[r] + d)];
            atomicAdd(&wsum[(rec.x >> 20) & 127], __uint_as_float(rec.y));
        }
    }
    __syncthreads();

    if (t < BNODES) {
        int node = b * BNODES + t;
        if (node < NN) dinv[node] = rsqrtf(wsum[t] + 1.0f);   // +1 = self-loop
    }
}

// ---------------- W1 -> bf16 MFMA B-fragments, lane-packed ----------------
__global__ void k_w1frag(const float* __restrict__ W1, unsigned short* __restrict__ wfrag) {
    int lane = threadIdx.x;   // 64 threads
    int q = lane >> 4;
    int n0 = lane & 15;
#pragma unroll
    for (int ks = 0; ks < 4; ks++) {
#pragma unroll
        for (int nt = 0; nt < 2; nt++) {
            int fi = ks * 2 + nt;
            int n = n0 + 16 * nt;
#pragma unroll
            for (int j = 0; j < 8; j++) {
                int k = ks * 32 + q * 8 + j;
                float v = W1[k * HID + n];
                __hip_bfloat16 bv = __float2bfloat16(v);
                wfrag[((size_t)fi * 64 + lane) * 8 + j] = *(unsigned short*)&bv;
            }
        }
    }
}

// ---------------- hs = dinv * (x @ W1) via MFMA, stored bf16 ----------------
__global__ __launch_bounds__(256) void k_hs(const float* __restrict__ x,
                                            const unsigned short* __restrict__ wfrag,
                                            const float* __restrict__ dinv,
                                            bf16* __restrict__ hs) {
    int t = threadIdx.x;
    int lane = t & 63;
    int wv = t >> 6;
    int base = blockIdx.x * 64 + wv * 16;
    int m = lane & 15;
    int q = lane >> 4;
    int node = base + m;

    s16x8 wf[8];
    const s16x8* wp = (const s16x8*)wfrag;
#pragma unroll
    for (int fi = 0; fi < 8; fi++) wf[fi] = wp[fi * 64 + lane];

    f32x4 acc0 = {0.f, 0.f, 0.f, 0.f};
    f32x4 acc1 = {0.f, 0.f, 0.f, 0.f};

    const float* rowp = x + (size_t)node * IN_F + q * 8;
    bool valid = (node < NN);

#pragma unroll
    for (int ks = 0; ks < 4; ks++) {
        float4 f0 = {0,0,0,0}, f1 = {0,0,0,0};
        if (valid) {
            const float4* xr = (const float4*)(rowp + ks * 32);
            f0 = xr[0]; f1 = xr[1];
        }
        union { s16x8 v; unsigned u32[4]; } af;
        __hip_bfloat162 p0 = __float22bfloat162_rn({f0.x, f0.y});
        __hip_bfloat162 p1 = __float22bfloat162_rn({f0.z, f0.w});
        __hip_bfloat162 p2 = __float22bfloat162_rn({f1.x, f1.y});
        __hip_bfloat162 p3 = __float22bfloat162_rn({f1.z, f1.w});
        af.u32[0] = *(unsigned*)&p0;
        af.u32[1] = *(unsigned*)&p1;
        af.u32[2] = *(unsigned*)&p2;
        af.u32[3] = *(unsigned*)&p3;
        acc0 = __builtin_amdgcn_mfma_f32_16x16x32_bf16(af.v, wf[ks * 2 + 0], acc0, 0, 0, 0);
        acc1 = __builtin_amdgcn_mfma_f32_16x16x32_bf16(af.v, wf[ks * 2 + 1], acc1, 0, 0, 0);
    }

    int f = lane & 15;
#pragma unroll
    for (int r = 0; r < 4; r++) {
        int n2 = base + q * 4 + r;
        if (n2 < NN) {
            float dv = dinv[n2];
            hs[(size_t)n2 * HID + f]      = __float2bfloat16(dv * acc0[r]);
            hs[(size_t)n2 * HID + f + 16] = __float2bfloat16(dv * acc1[r]);
        }
    }
}

// ---------------- fused: per-bucket gather + LDS counting sort + register pull + epilogue ----
// 36 KB LDS -> 4 blocks/CU (32 waves) for 2x the outstanding-gather concurrency.
__global__ __launch_bounds__(512) void k_agg(const int* __restrict__ offs,
                                             const uint2* __restrict__ raw,
                                             const bf16* __restrict__ hs,
                                             const float* __restrict__ dinv,
                                             const float* __restrict__ b1, const float* __restrict__ W2,
                                             const float* __restrict__ b2, float* __restrict__ out) {
    __shared__ uint2 se[SSPAN];               // 28.7 KB (sorted records); aliased by runid in phase A
    __shared__ int P[PBLK + 1];               //  3.1 KB
    __shared__ int basearr[PBLK];             //  3.1 KB  (= O0[r] - P[r])
    __shared__ int hist[BNODES];
    __shared__ int scanbuf[BNODES];
    __shared__ int cur[BNODES];
    __shared__ int wt8[8];

    unsigned short* runid = (unsigned short*)se;   // dead before se is written

    int t = threadIdx.x;
    int b = blockIdx.x;
    if (t < BNODES) hist[t] = 0;

    // run lengths for this bucket across 768 partition blocks (2 per thread, offs columns)
    int e0 = 2 * t, e1 = 2 * t + 1;
    int l0 = 0, l1 = 0, o0v = 0, o1v = 0;
    if (e0 < PBLK) {
        o0v = offs[(size_t)e0 * NBP1 + b];
        l0  = offs[(size_t)e0 * NBP1 + b + 1] - o0v;
    }
    if (e1 < PBLK) {
        o1v = offs[(size_t)e1 * NBP1 + b];
        l1  = offs[(size_t)e1 * NBP1 + b + 1] - o1v;
    }
    int psum = l0 + l1;
    int lane = t & 63;
    int incl = psum;
#pragma unroll
    for (int off = 1; off < 64; off <<= 1) {
        int up = __shfl_up(incl, off, 64);
        if (lane >= off) incl += up;
    }
    int wid = t >> 6;
    if (lane == 63) wt8[wid] = incl;
    __syncthreads();
    int woff = 0;
    for (int wj = 0; wj < wid; wj++) woff += wt8[wj];
    int exc = woff + incl - psum;
    if (e0 < PBLK) { P[e0] = exc;      basearr[e0] = o0v - exc; }
    if (e1 < PBLK) { P[e1] = exc + l0; basearr[e1] = o1v - (exc + l0); }
    if (t == 0) {
        int s = 0;
#pragma unroll
        for (int j = 0; j < 8; j++) s += wt8[j];
        P[PBLK] = s;
    }
    __syncthreads();

    int total = min(P[PBLK], SSPAN);

    // build d -> run map in the se region (short serial LDS fills, ~4 per run)
    for (int r = t; r < PBLK; r += 512) {
        int p0 = P[r], p1 = min(P[r + 1], SSPAN);
        for (int i = p0; i < p1; i++) runid[i] = (unsigned short)r;
    }
    __syncthreads();

    // pass 1: coalesced gather into REGISTERS + node histogram (<=7 recs/thread)
    uint2 rr[7];
#pragma unroll
    for (int k = 0; k < 7; k++) {
        int d = t + k * 512;
        if (d < total) {
            int r = runid[d];
            uint2 rec = raw[(size_t)r * EPB + (basearr[r] + d)];
            rr[k] = rec;
            int dl = (rec.x >> 20) & 127;
            atomicAdd(&hist[dl], 1);
        }
    }
    __syncthreads();   // runid dead from here; se region reusable

    // inclusive scan of node hist (Hillis-Steele over 98)
    if (t < BNODES) scanbuf[t] = hist[t];
    __syncthreads();
    for (int off = 1; off < BNODES; off <<= 1) {
        int v = 0;
        if (t < BNODES && t >= off) v = scanbuf[t - off];
        __syncthreads();
        if (t < BNODES) scanbuf[t] += v;
        __syncthreads();
    }
    if (t < BNODES) cur[t] = scanbuf[t] - hist[t];   // exclusive start
    __syncthreads();

    // pass 2: scatter from registers into se at final sorted positions
#pragma unroll
    for (int k = 0; k < 7; k++) {
        int d = t + k * 512;
        if (d < total) {
            uint2 rec = rr[k];
            int dl = (rec.x >> 20) & 127;
            int pos = atomicAdd(&cur[dl], 1);   // LDS int atomic
            se[pos] = make_uint2(rec.x & 0xFFFFF, rec.y);
        }
    }
    __syncthreads();

    // ---- phase B: per-group pull, register accumulate, fused epilogue ----
    // Full 8-blocks are unclamped (no cndmask chains); at most ONE clamped tail block.
    int gid = t >> 4;          // 0..31, 16 lanes each
    int l = t & 15;
    const __hip_bfloat162* hs2 = (const __hip_bfloat162*)hs;  // row stride 16
    for (int dl = gid; dl < BNODES; dl += 32) {
        int cnt = hist[dl];
        int rs = scanbuf[dl] - cnt;
        float a0 = 0.f, a1 = 0.f;
        int full = cnt & ~7;
        int bse = 0;
        for (; bse < full; bse += 8) {
            uint2 q0 = se[rs + bse + 0];
            uint2 q1 = se[rs + bse + 1];
            uint2 q2 = se[rs + bse + 2];
            uint2 q3 = se[rs + bse + 3];
            uint2 q4 = se[rs + bse + 4];
            uint2 q5 = se[rs + bse + 5];
            uint2 q6 = se[rs + bse + 6];
            uint2 q7 = se[rs + bse + 7];
            __hip_bfloat162 h0 = hs2[(size_t)q0.x * 16 + l];
            __hip_bfloat162 h1 = hs2[(size_t)q1.x * 16 + l];
            __hip_bfloat162 h2 = hs2[(size_t)q2.x * 16 + l];
            __hip_bfloat162 h3 = hs2[(size_t)q3.x * 16 + l];
            __hip_bfloat162 h4 = hs2[(size_t)q4.x * 16 + l];
            __hip_bfloat162 h5 = hs2[(size_t)q5.x * 16 + l];
            __hip_bfloat162 h6 = hs2[(size_t)q6.x * 16 + l];
            __hip_bfloat162 h7 = hs2[(size_t)q7.x * 16 + l];
            float2 f0 = __bfloat1622float2(h0); a0 += __uint_as_float(q0.y) * f0.x; a1 += __uint_as_float(q0.y) * f0.y;
            float2 f1 = __bfloat1622float2(h1); a0 += __uint_as_float(q1.y) * f1.x; a1 += __uint_as_float(q1.y) * f1.y;
            float2 f2 = __bfloat1622float2(h2); a0 += __uint_as_float(q2.y) * f2.x; a1 += __uint_as_float(q2.y) * f2.y;
            float2 f3 = __bfloat1622float2(h3); a0 += __uint_as_float(q3.y) * f3.x; a1 += __uint_as_float(q3.y) * f3.y;
            float2 f4 = __bfloat1622float2(h4); a0 += __uint_as_float(q4.y) * f4.x; a1 += __uint_as_float(q4.y) * f4.y;
            float2 f5 = __bfloat1622float2(h5); a0 += __uint_as_float(q5.y) * f5.x; a1 += __uint_as_float(q5.y) * f5.y;
            float2 f6 = __bfloat1622float2(h6); a0 += __uint_as_float(q6.y) * f6.x; a1 += __uint_as_float(q6.y) * f6.y;
            float2 f7 = __bfloat1622float2(h7); a0 += __uint_as_float(q7.y) * f7.x; a1 += __uint_as_float(q7.y) * f7.y;
        }
        if (bse < cnt) {
            int rem = cnt - bse;   // 1..7
            uint2 q0 = se[rs + bse];
            uint2 q1 = se[rs + bse + (rem > 1 ? 1 : 0)];
            uint2 q2 = se[rs + bse + (rem > 2 ? 2 : 0)];
            uint2 q3 = se[rs + bse + (rem > 3 ? 3 : 0)];
            uint2 q4 = se[rs + bse + (rem > 4 ? 4 : 0)];
            uint2 q5 = se[rs + bse + (rem > 5 ? 5 : 0)];
            uint2 q6 = se[rs + bse + (rem > 6 ? 6 : 0)];
            float w0 = __uint_as_float(q0.y);
            float w1 = rem > 1 ? __uint_as_float(q1.y) : 0.f;
            float w2 = rem > 2 ? __uint_as_float(q2.y) : 0.f;
            float w3 = rem > 3 ? __uint_as_float(q3.y) : 0.f;
            float w4 = rem > 4 ? __uint_as_float(q4.y) : 0.f;
            float w5 = rem > 5 ? __uint_as_float(q5.y) : 0.f;
            float w6 = rem > 6 ? __uint_as_float(q6.y) : 0.f;
            __hip_bfloat162 h0 = hs2[(size_t)q0.x * 16 + l];
            __hip_bfloat162 h1 = hs2[(size_t)q1.x * 16 + l];
            __hip_bfloat162 h2 = hs2[(size_t)q2.x * 16 + l];
            __hip_bfloat162 h3 = hs2[(size_t)q3.x * 16 + l];
            __hip_bfloat162 h4 = hs2[(size_t)q4.x * 16 + l];
            __hip_bfloat162 h5 = hs2[(size_t)q5.x * 16 + l];
            __hip_bfloat162 h6 = hs2[(size_t)q6.x * 16 + l];
            float2 f0 = __bfloat1622float2(h0); a0 += w0 * f0.x; a1 += w0 * f0.y;
            float2 f1 = __bfloat1622float2(h1); a0 += w1 * f1.x; a1 += w1 * f1.y;
            float2 f2 = __bfloat1622float2(h2); a0 += w2 * f2.x; a1 += w2 * f2.y;
            float2 f3 = __bfloat1622float2(h3); a0 += w3 * f3.x; a1 += w3 * f3.y;
            float2 f4 = __bfloat1622float2(h4); a0 += w4 * f4.x; a1 += w4 * f4.y;
            float2 f5 = __bfloat1622float2(h5); a0 += w5 * f5.x; a1 += w5 * f5.y;
            float2 f6 = __bfloat1622float2(h6); a0 += w6 * f6.x; a1 += w6 * f6.y;
        }
        int node = b * BNODES + dl;
        if (node < NN) {
            float dv = dinv[node];
            float2 fs = __bfloat1622float2(hs2[(size_t)node * 16 + l]);
            float v0 = dv * (a0 + fs.x) + b1[2 * l];
            float v1 = dv * (a1 + fs.y) + b1[2 * l + 1];
            v0 = fmaxf(v0, 0.f);
            v1 = fmaxf(v1, 0.f);
            float ps = v0 * W2[2 * l] + v1 * W2[2 * l + 1];
#pragma unroll
            for (int m2 = 8; m2 >= 1; m2 >>= 1) ps += __shfl_xor(ps, m2, 16);
            if (l == 0) out[node] = ps + b2[0];
        }
    }
}

// ---------------- launch ----------------
extern "C" void kernel_launch(void* const* d_in, const int* in_sizes, int n_in,
                              void* d_out, int out_size, void* d_ws, size_t ws_size,
                              hipStream_t stream) {
    const float* x  = (const float*)d_in[0];
    const int*   ei = (const int*)d_in[1];
    const float* ew = (const float*)d_in[2];
    const float* W1 = (const float*)d_in[3];
    const float* b1 = (const float*)d_in[4];
    const float* W2 = (const float*)d_in[5];
    const float* b2 = (const float*)d_in[6];
    float* out = (float*)d_out;

    char* ws = (char*)d_ws;
    // ws layout (bytes), total ~35.6 MB. No transpose buffer anymore.
    uint2*          raw      = (uint2*)         (ws + 0);           // PBLK*EPB uint2 = 25,608,192
    int*            offs     = (int*)           (ws + 25608192);    // PBLK*NBP1 int = 3,139,584 -> 28,747,776
    bf16*           hs       = (bf16*)          (ws + 28747776);    // NN*HID bf16 = 6,400,000 -> 35,147,776
    float*          dinv     = (float*)         (ws + 35147776);    // NN floats -> 35,547,776
    unsigned short* wfrag    = (unsigned short*)(ws + 35547776);    // 8 KB -> 35,555,968

    k_w1frag<<<1, 64, 0, stream>>>(W1, wfrag);
    k_part<<<PBLK, 512, 0, stream>>>(ei, ew, offs, raw);
    k_deg<<<NB, 512, 0, stream>>>(offs, raw, dinv);
    k_hs<<<(NN + 63) / 64, 256, 0, stream>>>(x, wfrag, dinv, hs);
    k_agg<<<NB, 512, 0, stream>>>(offs, raw, hs, dinv, b1, W2, b2, out);
}

// Round 10
// 202.941 us; speedup vs baseline: 1.0548x; 1.0548x over previous
//
#include <hip/hip_runtime.h>
#include <hip/hip_bf16.h>
#include <hip/hip_fp16.h>

#define NN 100000
#define NE 3200000
#define IN_F 128
#define HID 32

#define BNODES 131      // nodes per bucket
#define NB 764          // ceil(NN/BNODES) -> ~3.0 blocks/CU on 256 CUs
#define NBP1 (NB + 1)
#define PBLK 768        // partition blocks -> 3.0 blocks/CU
#define EPB 4168        // ceil(NE/PBLK) edges per partition block (even)
#define SSPAN 4736      // per-bucket span bound: mean 4192 + 8 sigma (65)

typedef __hip_bfloat16 bf16;
typedef __attribute__((ext_vector_type(8))) short s16x8;   // 8 bf16 (4 VGPRs)
typedef __attribute__((ext_vector_type(4))) float f32x4;   // MFMA C/D

// ---------------- partition: LDS counting sort, ALL global writes dense ----------------
__global__ __launch_bounds__(512) void k_part(const int* __restrict__ ei,
                                              const float* __restrict__ ew,
                                              int* __restrict__ offs,
                                              uint2* __restrict__ raw) {
    __shared__ int hist[NB];
    __shared__ int start[NB];
    __shared__ int wtot8[8];
    __shared__ __align__(16) uint2 sp[EPB];   // 33.3 KB

    int t = threadIdx.x;
    int blk = blockIdx.x;
    for (int b = t; b < NB; b += 512) hist[b] = 0;
    __syncthreads();

    unsigned pk[10]; unsigned wb[10]; int bkt[10];
    int base_e = blk * EPB;
#pragma unroll
    for (int j = 0; j < 5; j++) {
        int p = j * 512 + t;               // pair index within block
        int e = base_e + 2 * p;
        bool v = (p < (EPB / 2)) && (e < NE);
        if (v) {
            int2   s2 = *(const int2*)(ei + e);
            int2   d2 = *(const int2*)(ei + NE + e);
            float2 w2 = *(const float2*)(ew + e);
            int bk0 = d2.x / BNODES;           // magic-mul by compiler
            bkt[2 * j]     = bk0;
            pk[2 * j]      = (unsigned)s2.x | ((unsigned)(d2.x - bk0 * BNODES) << 20);
            wb[2 * j]      = __float_as_uint(w2.x);
            int bk1 = d2.y / BNODES;
            bkt[2 * j + 1] = bk1;
            pk[2 * j + 1]  = (unsigned)s2.y | ((unsigned)(d2.y - bk1 * BNODES) << 20);
            wb[2 * j + 1]  = __float_as_uint(w2.y);
        } else { bkt[2 * j] = -1; bkt[2 * j + 1] = -1; }
    }
#pragma unroll
    for (int j = 0; j < 10; j++)
        if (bkt[j] >= 0) atomicAdd(&hist[bkt[j]], 1);
    __syncthreads();

    // exclusive scan over 764 bins (2 per thread, shuffle-based)
    int e0 = 2 * t, e1 = 2 * t + 1;
    int h0 = (e0 < NB) ? hist[e0] : 0;
    int h1 = (e1 < NB) ? hist[e1] : 0;
    int psum = h0 + h1;
    int lane = t & 63;
    int incl = psum;
#pragma unroll
    for (int off = 1; off < 64; off <<= 1) {
        int up = __shfl_up(incl, off, 64);
        if (lane >= off) incl += up;
    }
    int wid = t >> 6;
    if (lane == 63) wtot8[wid] = incl;
    __syncthreads();
    int woff = 0;
    for (int wj = 0; wj < wid; wj++) woff += wtot8[wj];
    int exc = woff + incl - psum;
    if (e0 < NB) start[e0] = exc;
    if (e1 < NB) start[e1] = exc + h0;
    __syncthreads();

    int total = start[NB - 1] + hist[NB - 1];
    int* orow = offs + (size_t)blk * NBP1;
    for (int b = t; b < NB; b += 512) orow[b] = start[b];
    if (t == 0) orow[NB] = total;
    __syncthreads();   // orow reads of start[] complete before cursor mutation

    // LDS counting scatter (start[] becomes cursor)
#pragma unroll
    for (int j = 0; j < 10; j++) {
        if (bkt[j] >= 0) {
            int pos = atomicAdd(&start[bkt[j]], 1);
            sp[pos] = make_uint2(pk[j], wb[j]);
        }
    }
    __syncthreads();

    // dense, coalesced 16B copy to block-private region (written exactly once)
    uint2* r = raw + (size_t)blk * EPB;    // EPB*8 bytes, 16B-aligned per block
    int tot2 = total >> 1;
    const uint4* sp4 = (const uint4*)sp;
    uint4* r4 = (uint4*)r;
    for (int i = t; i < tot2; i += 512) r4[i] = sp4[i];
    if (t == 0 && (total & 1)) r[total - 1] = sp[total - 1];
}

// ---------------- offs transpose ([blk][bucket] -> [bucket][blk]) ----------------
// Restored: column reads of offs cost a 64-B line per run (50 MB aggregate, round-9
// regression); transposed rows are contiguous (3 MB aggregate).
__global__ __launch_bounds__(256) void k_trans(const int* __restrict__ in, int* __restrict__ out) {
    __shared__ int tile[32][33];
    int c0 = blockIdx.x * 32, r0 = blockIdx.y * 32;
    int tx = threadIdx.x & 31, ty = threadIdx.x >> 5;   // 32 x 8
    for (int i = ty; i < 32; i += 8) {
        int r = r0 + i, c = c0 + tx;
        if (r < PBLK && c < NBP1) tile[i][tx] = in[(size_t)r * NBP1 + c];
    }
    __syncthreads();
    for (int i = ty; i < 32; i += 8) {
        int c = c0 + i, r = r0 + tx;
        if (c < NBP1 && r < PBLK) out[(size_t)c * PBLK + r] = tile[tx][i];
    }
}

// ---------------- per-bucket weighted degree -> dinv (LDS atomics, dense writes) ----------
__global__ __launch_bounds__(512) void k_deg(const int* __restrict__ offsT,
                                             const uint2* __restrict__ raw,
                                             float* __restrict__ dinv) {
    __shared__ unsigned short runid[SSPAN];   //  9.5 KB
    __shared__ int P[PBLK + 1];               //  3.1 KB
    __shared__ int basearr[PBLK];             //  3.1 KB  (= O0[r] - P[r])
    __shared__ float wsum[BNODES];
    __shared__ int wt8[8];

    int t = threadIdx.x;
    int b = blockIdx.x;
    if (t < BNODES) wsum[t] = 0.f;

    int e0 = 2 * t, e1 = 2 * t + 1;
    int l0 = 0, l1 = 0, o0v = 0, o1v = 0;
    if (e0 < PBLK) {
        o0v = offsT[(size_t)b * PBLK + e0];
        l0  = offsT[(size_t)(b + 1) * PBLK + e0] - o0v;
    }
    if (e1 < PBLK) {
        o1v = offsT[(size_t)b * PBLK + e1];
        l1  = offsT[(size_t)(b + 1) * PBLK + e1] - o1v;
    }
    int psum = l0 + l1;
    int lane = t & 63;
    int incl = psum;
#pragma unroll
    for (int off = 1; off < 64; off <<= 1) {
        int up = __shfl_up(incl, off, 64);
        if (lane >= off) incl += up;
    }
    int wid = t >> 6;
    if (lane == 63) wt8[wid] = incl;
    __syncthreads();          // covers wsum init
    int woff = 0;
    for (int wj = 0; wj < wid; wj++) woff += wt8[wj];
    int exc = woff + incl - psum;
    if (e0 < PBLK) { P[e0] = exc;      basearr[e0] = o0v - exc; }
    if (e1 < PBLK) { P[e1] = exc + l0; basearr[e1] = o1v - (exc + l0); }
    if (t == 0) {
        int s = 0;
#pragma unroll
        for (int j = 0; j < 8; j++) s += wt8[j];
        P[PBLK] = s;
    }
    __syncthreads();

    int total = min(P[PBLK], SSPAN);

    for (int r = t; r < PBLK; r += 512) {
        int p0 = P[r], p1 = min(P[r + 1], SSPAN);
        for (int i = p0; i < p1; i++) runid[i] = (unsigned short)r;
    }
    __syncthreads();

#pragma unroll
    for (int k = 0; k < 10; k++) {
        int d = t + k * 512;
        if (d < total) {
            int r = runid[d];
            uint2 rec = raw[(size_t)r * EPB + (basearr[r] + d)];
            atomicAdd(&wsum[(rec.x >> 20) & 255], __uint_as_float(rec.y));
        }
    }
    __syncthreads();

    if (t < BNODES) {
        int node = b * BNODES + t;
        if (node < NN) dinv[node] = rsqrtf(wsum[t] + 1.0f);   // +1 = self-loop
    }
}

// ---------------- W1 -> bf16 MFMA B-fragments, lane-packed ----------------
__global__ void k_w1frag(const float* __restrict__ W1, unsigned short* __restrict__ wfrag) {
    int lane = threadIdx.x;   // 64 threads
    int q = lane >> 4;
    int n0 = lane & 15;
#pragma unroll
    for (int ks = 0; ks < 4; ks++) {
#pragma unroll
        for (int nt = 0; nt < 2; nt++) {
            int fi = ks * 2 + nt;
            int n = n0 + 16 * nt;
#pragma unroll
            for (int j = 0; j < 8; j++) {
                int k = ks * 32 + q * 8 + j;
                float v = W1[k * HID + n];
                __hip_bfloat16 bv = __float2bfloat16(v);
                wfrag[((size_t)fi * 64 + lane) * 8 + j] = *(unsigned short*)&bv;
            }
        }
    }
}

// ---------------- hs = dinv * (x @ W1) via MFMA, stored bf16 ----------------
__global__ __launch_bounds__(256) void k_hs(const float* __restrict__ x,
                                            const unsigned short* __restrict__ wfrag,
                                            const float* __restrict__ dinv,
                                            bf16* __restrict__ hs) {
    int t = threadIdx.x;
    int lane = t & 63;
    int wv = t >> 6;
    int base = blockIdx.x * 64 + wv * 16;
    int m = lane & 15;
    int q = lane >> 4;
    int node = base + m;

    s16x8 wf[8];
    const s16x8* wp = (const s16x8*)wfrag;
#pragma unroll
    for (int fi = 0; fi < 8; fi++) wf[fi] = wp[fi * 64 + lane];

    f32x4 acc0 = {0.f, 0.f, 0.f, 0.f};
    f32x4 acc1 = {0.f, 0.f, 0.f, 0.f};

    const float* rowp = x + (size_t)node * IN_F + q * 8;
    bool valid = (node < NN);

#pragma unroll
    for (int ks = 0; ks < 4; ks++) {
        float4 f0 = {0,0,0,0}, f1 = {0,0,0,0};
        if (valid) {
            const float4* xr = (const float4*)(rowp + ks * 32);
            f0 = xr[0]; f1 = xr[1];
        }
        union { s16x8 v; unsigned u32[4]; } af;
        __hip_bfloat162 p0 = __float22bfloat162_rn({f0.x, f0.y});
        __hip_bfloat162 p1 = __float22bfloat162_rn({f0.z, f0.w});
        __hip_bfloat162 p2 = __float22bfloat162_rn({f1.x, f1.y});
        __hip_bfloat162 p3 = __float22bfloat162_rn({f1.z, f1.w});
        af.u32[0] = *(unsigned*)&p0;
        af.u32[1] = *(unsigned*)&p1;
        af.u32[2] = *(unsigned*)&p2;
        af.u32[3] = *(unsigned*)&p3;
        acc0 = __builtin_amdgcn_mfma_f32_16x16x32_bf16(af.v, wf[ks * 2 + 0], acc0, 0, 0, 0);
        acc1 = __builtin_amdgcn_mfma_f32_16x16x32_bf16(af.v, wf[ks * 2 + 1], acc1, 0, 0, 0);
    }

    int f = lane & 15;
#pragma unroll
    for (int r = 0; r < 4; r++) {
        int n2 = base + q * 4 + r;
        if (n2 < NN) {
            float dv = dinv[n2];
            hs[(size_t)n2 * HID + f]      = __float2bfloat16(dv * acc0[r]);
            hs[(size_t)n2 * HID + f + 16] = __float2bfloat16(dv * acc1[r]);
        }
    }
}

// ---------------- fused: per-bucket gather + LDS counting sort + register pull + epilogue ----
// ~45.6 KB LDS -> 3 blocks/CU (24 waves) for +50% outstanding-gather concurrency vs 2/CU.
__global__ __launch_bounds__(512) void k_agg(const int* __restrict__ offsT,
                                             const uint2* __restrict__ raw,
                                             const bf16* __restrict__ hs,
                                             const float* __restrict__ dinv,
                                             const float* __restrict__ b1, const float* __restrict__ W2,
                                             const float* __restrict__ b2, float* __restrict__ out) {
    __shared__ uint2 se[SSPAN];               // 37.9 KB (sorted records); aliased by runid in phase A
    __shared__ int P[PBLK + 1];               //  3.1 KB
    __shared__ int basearr[PBLK];             //  3.1 KB  (= O0[r] - P[r])
    __shared__ int hist[BNODES];
    __shared__ int scanbuf[BNODES];
    __shared__ int cur[BNODES];
    __shared__ int wt8[8];

    unsigned short* runid = (unsigned short*)se;   // dead before se is written

    int t = threadIdx.x;
    int b = blockIdx.x;
    if (t < BNODES) hist[t] = 0;

    // run lengths for this bucket across 768 partition blocks (2 per thread)
    int e0 = 2 * t, e1 = 2 * t + 1;
    int l0 = 0, l1 = 0, o0v = 0, o1v = 0;
    if (e0 < PBLK) {
        o0v = offsT[(size_t)b * PBLK + e0];
        l0  = offsT[(size_t)(b + 1) * PBLK + e0] - o0v;
    }
    if (e1 < PBLK) {
        o1v = offsT[(size_t)b * PBLK + e1];
        l1  = offsT[(size_t)(b + 1) * PBLK + e1] - o1v;
    }
    int psum = l0 + l1;
    int lane = t & 63;
    int incl = psum;
#pragma unroll
    for (int off = 1; off < 64; off <<= 1) {
        int up = __shfl_up(incl, off, 64);
        if (lane >= off) incl += up;
    }
    int wid = t >> 6;
    if (lane == 63) wt8[wid] = incl;
    __syncthreads();
    int woff = 0;
    for (int wj = 0; wj < wid; wj++) woff += wt8[wj];
    int exc = woff + incl - psum;
    if (e0 < PBLK) { P[e0] = exc;      basearr[e0] = o0v - exc; }
    if (e1 < PBLK) { P[e1] = exc + l0; basearr[e1] = o1v - (exc + l0); }
    if (t == 0) {
        int s = 0;
#pragma unroll
        for (int j = 0; j < 8; j++) s += wt8[j];
        P[PBLK] = s;
    }
    __syncthreads();

    int total = min(P[PBLK], SSPAN);

    // build d -> run map in the se region (short serial LDS fills, ~6 per run)
    for (int r = t; r < PBLK; r += 512) {
        int p0 = P[r], p1 = min(P[r + 1], SSPAN);
        for (int i = p0; i < p1; i++) runid[i] = (unsigned short)r;
    }
    __syncthreads();

    // pass 1: coalesced gather into REGISTERS + node histogram (<=10 recs/thread)
    uint2 rr[10];
#pragma unroll
    for (int k = 0; k < 10; k++) {
        int d = t + k * 512;
        if (d < total) {
            int r = runid[d];
            uint2 rec = raw[(size_t)r * EPB + (basearr[r] + d)];
            rr[k] = rec;
            int dl = (rec.x >> 20) & 255;
            atomicAdd(&hist[dl], 1);
        }
    }
    __syncthreads();   // runid dead from here; se region reusable

    // inclusive scan of node hist (Hillis-Steele over 131)
    if (t < BNODES) scanbuf[t] = hist[t];
    __syncthreads();
    for (int off = 1; off < BNODES; off <<= 1) {
        int v = 0;
        if (t < BNODES && t >= off) v = scanbuf[t - off];
        __syncthreads();
        if (t < BNODES) scanbuf[t] += v;
        __syncthreads();
    }
    if (t < BNODES) cur[t] = scanbuf[t] - hist[t];   // exclusive start
    __syncthreads();

    // pass 2: scatter from registers into se at final sorted positions
#pragma unroll
    for (int k = 0; k < 10; k++) {
        int d = t + k * 512;
        if (d < total) {
            uint2 rec = rr[k];
            int dl = (rec.x >> 20) & 255;
            int pos = atomicAdd(&cur[dl], 1);   // LDS int atomic
            se[pos] = make_uint2(rec.x & 0xFFFFF, rec.y);
        }
    }
    __syncthreads();

    // ---- phase B: per-group pull, register accumulate, fused epilogue ----
    // Full 8-blocks are unclamped (no cndmask chains); at most ONE clamped tail block.
    int gid = t >> 4;          // 0..31, 16 lanes each
    int l = t & 15;
    const __hip_bfloat162* hs2 = (const __hip_bfloat162*)hs;  // row stride 16
    for (int dl = gid; dl < BNODES; dl += 32) {
        int cnt = hist[dl];
        int rs = scanbuf[dl] - cnt;
        float a0 = 0.f, a1 = 0.f;
        int full = cnt & ~7;
        int bse = 0;
        for (; bse < full; bse += 8) {
            uint2 q0 = se[rs + bse + 0];
            uint2 q1 = se[rs + bse + 1];
            uint2 q2 = se[rs + bse + 2];
            uint2 q3 = se[rs + bse + 3];
            uint2 q4 = se[rs + bse + 4];
            uint2 q5 = se[rs + bse + 5];
            uint2 q6 = se[rs + bse + 6];
            uint2 q7 = se[rs + bse + 7];
            __hip_bfloat162 h0 = hs2[(size_t)q0.x * 16 + l];
            __hip_bfloat162 h1 = hs2[(size_t)q1.x * 16 + l];
            __hip_bfloat162 h2 = hs2[(size_t)q2.x * 16 + l];
            __hip_bfloat162 h3 = hs2[(size_t)q3.x * 16 + l];
            __hip_bfloat162 h4 = hs2[(size_t)q4.x * 16 + l];
            __hip_bfloat162 h5 = hs2[(size_t)q5.x * 16 + l];
            __hip_bfloat162 h6 = hs2[(size_t)q6.x * 16 + l];
            __hip_bfloat162 h7 = hs2[(size_t)q7.x * 16 + l];
            float2 f0 = __bfloat1622float2(h0); a0 += __uint_as_float(q0.y) * f0.x; a1 += __uint_as_float(q0.y) * f0.y;
            float2 f1 = __bfloat1622float2(h1); a0 += __uint_as_float(q1.y) * f1.x; a1 += __uint_as_float(q1.y) * f1.y;
            float2 f2 = __bfloat1622float2(h2); a0 += __uint_as_float(q2.y) * f2.x; a1 += __uint_as_float(q2.y) * f2.y;
            float2 f3 = __bfloat1622float2(h3); a0 += __uint_as_float(q3.y) * f3.x; a1 += __uint_as_float(q3.y) * f3.y;
            float2 f4 = __bfloat1622float2(h4); a0 += __uint_as_float(q4.y) * f4.x; a1 += __uint_as_float(q4.y) * f4.y;
            float2 f5 = __bfloat1622float2(h5); a0 += __uint_as_float(q5.y) * f5.x; a1 += __uint_as_float(q5.y) * f5.y;
            float2 f6 = __bfloat1622float2(h6); a0 += __uint_as_float(q6.y) * f6.x; a1 += __uint_as_float(q6.y) * f6.y;
            float2 f7 = __bfloat1622float2(h7); a0 += __uint_as_float(q7.y) * f7.x; a1 += __uint_as_float(q7.y) * f7.y;
        }
        if (bse < cnt) {
            int rem = cnt - bse;   // 1..7
            uint2 q0 = se[rs + bse];
            uint2 q1 = se[rs + bse + (rem > 1 ? 1 : 0)];
            uint2 q2 = se[rs + bse + (rem > 2 ? 2 : 0)];
            uint2 q3 = se[rs + bse + (rem > 3 ? 3 : 0)];
            uint2 q4 = se[rs + bse + (rem > 4 ? 4 : 0)];
            uint2 q5 = se[rs + bse + (rem > 5 ? 5 : 0)];
            uint2 q6 = se[rs + bse + (rem > 6 ? 6 : 0)];
            float w0 = __uint_as_float(q0.y);
            float w1 = rem > 1 ? __uint_as_float(q1.y) : 0.f;
            float w2 = rem > 2 ? __uint_as_float(q2.y) : 0.f;
            float w3 = rem > 3 ? __uint_as_float(q3.y) : 0.f;
            float w4 = rem > 4 ? __uint_as_float(q4.y) : 0.f;
            float w5 = rem > 5 ? __uint_as_float(q5.y) : 0.f;
            float w6 = rem > 6 ? __uint_as_float(q6.y) : 0.f;
            __hip_bfloat162 h0 = hs2[(size_t)q0.x * 16 + l];
            __hip_bfloat162 h1 = hs2[(size_t)q1.x * 16 + l];
            __hip_bfloat162 h2 = hs2[(size_t)q2.x * 16 + l];
            __hip_bfloat162 h3 = hs2[(size_t)q3.x * 16 + l];
            __hip_bfloat162 h4 = hs2[(size_t)q4.x * 16 + l];
            __hip_bfloat162 h5 = hs2[(size_t)q5.x * 16 + l];
            __hip_bfloat162 h6 = hs2[(size_t)q6.x * 16 + l];
            float2 f0 = __bfloat1622float2(h0); a0 += w0 * f0.x; a1 += w0 * f0.y;
            float2 f1 = __bfloat1622float2(h1); a0 += w1 * f1.x; a1 += w1 * f1.y;
            float2 f2 = __bfloat1622float2(h2); a0 += w2 * f2.x; a1 += w2 * f2.y;
            float2 f3 = __bfloat1622float2(h3); a0 += w3 * f3.x; a1 += w3 * f3.y;
            float2 f4 = __bfloat1622float2(h4); a0 += w4 * f4.x; a1 += w4 * f4.y;
            float2 f5 = __bfloat1622float2(h5); a0 += w5 * f5.x; a1 += w5 * f5.y;
            float2 f6 = __bfloat1622float2(h6); a0 += w6 * f6.x; a1 += w6 * f6.y;
        }
        int node = b * BNODES + dl;
        if (node < NN) {
            float dv = dinv[node];
            float2 fs = __bfloat1622float2(hs2[(size_t)node * 16 + l]);
            float v0 = dv * (a0 + fs.x) + b1[2 * l];
            float v1 = dv * (a1 + fs.y) + b1[2 * l + 1];
            v0 = fmaxf(v0, 0.f);
            v1 = fmaxf(v1, 0.f);
            float ps = v0 * W2[2 * l] + v1 * W2[2 * l + 1];
#pragma unroll
            for (int m2 = 8; m2 >= 1; m2 >>= 1) ps += __shfl_xor(ps, m2, 16);
            if (l == 0) out[node] = ps + b2[0];
        }
    }
}

// ---------------- launch ----------------
extern "C" void kernel_launch(void* const* d_in, const int* in_sizes, int n_in,
                              void* d_out, int out_size, void* d_ws, size_t ws_size,
                              hipStream_t stream) {
    const float* x  = (const float*)d_in[0];
    const int*   ei = (const int*)d_in[1];
    const float* ew = (const float*)d_in[2];
    const float* W1 = (const float*)d_in[3];
    const float* b1 = (const float*)d_in[4];
    const float* W2 = (const float*)d_in[5];
    const float* b2 = (const float*)d_in[6];
    float* out = (float*)d_out;

    char* ws = (char*)d_ws;
    // ws layout (bytes), total ~37.1 MB.
    uint2*          raw      = (uint2*)         (ws + 0);           // PBLK*EPB uint2 = 25,608,192
    int*            offs     = (int*)           (ws + 25608192);    // PBLK*NBP1 int = 2,350,080 -> 27,958,272
    int*            offsT    = (int*)           (ws + 27958272);    // NBP1*PBLK int = 2,350,080 -> 30,308,352
    bf16*           hs       = (bf16*)          (ws + 30308352);    // NN*HID bf16 = 6,400,000 -> 36,708,352
    float*          dinv     = (float*)         (ws + 36708352);    // NN floats -> 37,108,352
    unsigned short* wfrag    = (unsigned short*)(ws + 37108352);    // 8 KB -> 37,116,544

    k_w1frag<<<1, 64, 0, stream>>>(W1, wfrag);
    k_part<<<PBLK, 512, 0, stream>>>(ei, ew, offs, raw);
    k_trans<<<dim3((NBP1 + 31) / 32, (PBLK + 31) / 32), 256, 0, stream>>>(offs, offsT);
    k_deg<<<NB, 512, 0, stream>>>(offsT, raw, dinv);
    k_hs<<<(NN + 63) / 64, 256, 0, stream>>>(x, wfrag, dinv, hs);
    k_agg<<<NB, 512, 0, stream>>>(offsT, raw, hs, dinv, b1, W2, b2, out);
}

// Round 12
// 199.918 us; speedup vs baseline: 1.0708x; 1.0151x over previous
//
#include <hip/hip_runtime.h>
#include <hip/hip_bf16.h>
#include <hip/hip_fp16.h>

#define NN 100000
#define NE 3200000
#define IN_F 128
#define HID 32

#define BNODES 131      // nodes per bucket
#define NB 764          // ceil(NN/BNODES) -> ~3.0 blocks/CU on 256 CUs
#define NBP1 (NB + 1)
#define PBLK 768        // partition blocks -> 3.0 blocks/CU
#define EPB 4168        // ceil(NE/PBLK) edges per partition block (even)
#define SSPAN 4736      // per-bucket span bound: mean 4188 + 8 sigma (65)

typedef __hip_bfloat16 bf16;
typedef __attribute__((ext_vector_type(8))) short s16x8;   // 8 bf16 (4 VGPRs)
typedef __attribute__((ext_vector_type(4))) float f32x4;   // MFMA C/D

// ---------------- partition: LDS counting sort, ALL global writes dense ----------------
__global__ __launch_bounds__(512) void k_part(const int* __restrict__ ei,
                                              const float* __restrict__ ew,
                                              int* __restrict__ offs,
                                              uint2* __restrict__ raw) {
    __shared__ int hist[NB];
    __shared__ int start[NB];
    __shared__ int wtot8[8];
    __shared__ __align__(16) uint2 sp[EPB];   // 33.3 KB

    int t = threadIdx.x;
    int blk = blockIdx.x;
    for (int b = t; b < NB; b += 512) hist[b] = 0;
    __syncthreads();

    unsigned pk[10]; unsigned wb[10]; int bkt[10];
    int base_e = blk * EPB;
#pragma unroll
    for (int j = 0; j < 5; j++) {
        int p = j * 512 + t;               // pair index within block
        int e = base_e + 2 * p;
        bool v = (p < (EPB / 2)) && (e < NE);
        if (v) {
            int2   s2 = *(const int2*)(ei + e);
            int2   d2 = *(const int2*)(ei + NE + e);
            float2 w2 = *(const float2*)(ew + e);
            int bk0 = d2.x / BNODES;           // magic-mul by compiler
            bkt[2 * j]     = bk0;
            pk[2 * j]      = (unsigned)s2.x | ((unsigned)(d2.x - bk0 * BNODES) << 20);
            wb[2 * j]      = __float_as_uint(w2.x);
            int bk1 = d2.y / BNODES;
            bkt[2 * j + 1] = bk1;
            pk[2 * j + 1]  = (unsigned)s2.y | ((unsigned)(d2.y - bk1 * BNODES) << 20);
            wb[2 * j + 1]  = __float_as_uint(w2.y);
        } else { bkt[2 * j] = -1; bkt[2 * j + 1] = -1; }
    }
#pragma unroll
    for (int j = 0; j < 10; j++)
        if (bkt[j] >= 0) atomicAdd(&hist[bkt[j]], 1);
    __syncthreads();

    // exclusive scan over 764 bins (2 per thread, shuffle-based)
    int e0 = 2 * t, e1 = 2 * t + 1;
    int h0 = (e0 < NB) ? hist[e0] : 0;
    int h1 = (e1 < NB) ? hist[e1] : 0;
    int psum = h0 + h1;
    int lane = t & 63;
    int incl = psum;
#pragma unroll
    for (int off = 1; off < 64; off <<= 1) {
        int up = __shfl_up(incl, off, 64);
        if (lane >= off) incl += up;
    }
    int wid = t >> 6;
    if (lane == 63) wtot8[wid] = incl;
    __syncthreads();
    int woff = 0;
    for (int wj = 0; wj < wid; wj++) woff += wtot8[wj];
    int exc = woff + incl - psum;
    if (e0 < NB) start[e0] = exc;
    if (e1 < NB) start[e1] = exc + h0;
    __syncthreads();

    int total = start[NB - 1] + hist[NB - 1];
    int* orow = offs + (size_t)blk * NBP1;
    for (int b = t; b < NB; b += 512) orow[b] = start[b];
    if (t == 0) orow[NB] = total;
    __syncthreads();   // orow reads of start[] complete before cursor mutation

    // LDS counting scatter (start[] becomes cursor)
#pragma unroll
    for (int j = 0; j < 10; j++) {
        if (bkt[j] >= 0) {
            int pos = atomicAdd(&start[bkt[j]], 1);
            sp[pos] = make_uint2(pk[j], wb[j]);
        }
    }
    __syncthreads();

    // dense, coalesced 16B copy to block-private region (written exactly once)
    uint2* r = raw + (size_t)blk * EPB;
    int tot2 = total >> 1;
    const uint4* sp4 = (const uint4*)sp;
    uint4* r4 = (uint4*)r;
    for (int i = t; i < tot2; i += 512) r4[i] = sp4[i];
    if (t == 0 && (total & 1)) r[total - 1] = sp[total - 1];
}

// ---------------- offs transpose ([blk][bucket] -> [bucket][blk]) ----------------
__global__ __launch_bounds__(256) void k_trans(const int* __restrict__ in, int* __restrict__ out) {
    __shared__ int tile[32][33];
    int c0 = blockIdx.x * 32, r0 = blockIdx.y * 32;
    int tx = threadIdx.x & 31, ty = threadIdx.x >> 5;   // 32 x 8
    for (int i = ty; i < 32; i += 8) {
        int r = r0 + i, c = c0 + tx;
        if (r < PBLK && c < NBP1) tile[i][tx] = in[(size_t)r * NBP1 + c];
    }
    __syncthreads();
    for (int i = ty; i < 32; i += 8) {
        int c = c0 + i, r = r0 + tx;
        if (c < NBP1 && r < PBLK) out[(size_t)c * PBLK + r] = tile[tx][i];
    }
}

// ---------------- fused per-bucket: degree -> dinv -> hs = dinv*(x@W1) via MFMA ----------
// One block per bucket. Phase A = k_deg (run scan + runid + coalesced gather + LDS f32
// atomics -> wsum -> dinvl, dinv written globally for k_agg). Phase B = k_hs for this
// bucket's CONTIGUOUS node range (9 MFMA tiles over 8 waves), W1 fragments built inline
// from L2-hot W1 (4 KB/block). Overlaps gather latency with MFMA across resident blocks.
__global__ __launch_bounds__(512) void k_dh(const int* __restrict__ offsT,
                                            const uint2* __restrict__ raw,
                                            const float* __restrict__ x,
                                            const float* __restrict__ W1,
                                            float* __restrict__ dinv,
                                            bf16* __restrict__ hs) {
    __shared__ unsigned short runid[SSPAN];   //  9.5 KB
    __shared__ int P[PBLK + 1];               //  3.1 KB
    __shared__ int basearr[PBLK];             //  3.1 KB
    __shared__ float wsumf[BNODES];
    __shared__ float dinvl[BNODES];
    __shared__ int wt8[8];

    int t = threadIdx.x;
    int b = blockIdx.x;
    if (t < BNODES) wsumf[t] = 0.f;

    int e0 = 2 * t, e1 = 2 * t + 1;
    int l0 = 0, l1 = 0, o0v = 0, o1v = 0;
    if (e0 < PBLK) {
        o0v = offsT[(size_t)b * PBLK + e0];
        l0  = offsT[(size_t)(b + 1) * PBLK + e0] - o0v;
    }
    if (e1 < PBLK) {
        o1v = offsT[(size_t)b * PBLK + e1];
        l1  = offsT[(size_t)(b + 1) * PBLK + e1] - o1v;
    }
    int psum = l0 + l1;
    int lane = t & 63;
    int incl = psum;
#pragma unroll
    for (int off = 1; off < 64; off <<= 1) {
        int up = __shfl_up(incl, off, 64);
        if (lane >= off) incl += up;
    }
    int wid = t >> 6;
    if (lane == 63) wt8[wid] = incl;
    __syncthreads();          // covers wsum init
    int woff = 0;
    for (int wj = 0; wj < wid; wj++) woff += wt8[wj];
    int exc = woff + incl - psum;
    if (e0 < PBLK) { P[e0] = exc;      basearr[e0] = o0v - exc; }
    if (e1 < PBLK) { P[e1] = exc + l0; basearr[e1] = o1v - (exc + l0); }
    if (t == 0) {
        int s = 0;
#pragma unroll
        for (int j = 0; j < 8; j++) s += wt8[j];
        P[PBLK] = s;
    }
    __syncthreads();

    int total = min(P[PBLK], SSPAN);

    for (int r = t; r < PBLK; r += 512) {
        int p0 = P[r], p1 = min(P[r + 1], SSPAN);
        for (int i = p0; i < p1; i++) runid[i] = (unsigned short)r;
    }
    __syncthreads();

#pragma unroll
    for (int k = 0; k < 10; k++) {
        int d = t + k * 512;
        if (d < total) {
            int r = runid[d];
            uint2 rec = raw[(size_t)r * EPB + (basearr[r] + d)];
            atomicAdd(&wsumf[(rec.x >> 20) & 255], __uint_as_float(rec.y));
        }
    }
    __syncthreads();

    if (t < BNODES) {
        float dv = rsqrtf(wsumf[t] + 1.0f);   // +1 = self-loop
        dinvl[t] = dv;
        int node = b * BNODES + t;
        if (node < NN) dinv[node] = dv;
    }
    __syncthreads();

    // ---- phase B: MFMA hs for this bucket's contiguous node range ----
    int wv = t >> 6;          // wave 0..7
    int m = lane & 15;
    int q = lane >> 4;

    // W1 -> B-fragments, inline (same mapping as k_w1frag)
    s16x8 wf[8];
    {
#pragma unroll
        for (int ks2 = 0; ks2 < 4; ks2++) {
#pragma unroll
            for (int nt = 0; nt < 2; nt++) {
                union { s16x8 v; unsigned short u[8]; } wu;
#pragma unroll
                for (int j = 0; j < 8; j++) {
                    int kk = ks2 * 32 + q * 8 + j;
                    __hip_bfloat16 bv = __float2bfloat16(W1[kk * HID + m + 16 * nt]);
                    wu.u[j] = *(unsigned short*)&bv;
                }
                wf[ks2 * 2 + nt] = wu.v;
            }
        }
    }

    // 9 tiles of 16 rows cover 131 local nodes; waves take tile = wv, wv+8
    for (int tile = wv; tile * 16 < BNODES; tile += 8) {
        int lrow = tile * 16 + m;             // local row this lane loads
        int node = b * BNODES + lrow;
        bool valid = (lrow < BNODES) && (node < NN);

        f32x4 acc0 = {0.f, 0.f, 0.f, 0.f};
        f32x4 acc1 = {0.f, 0.f, 0.f, 0.f};
        const float* rowp = x + (size_t)node * IN_F + q * 8;

#pragma unroll
        for (int ks = 0; ks < 4; ks++) {
            float4 f0 = {0,0,0,0}, f1 = {0,0,0,0};
            if (valid) {
                const float4* xr = (const float4*)(rowp + ks * 32);
                f0 = xr[0]; f1 = xr[1];
            }
            union { s16x8 v; unsigned u32[4]; } af;
            __hip_bfloat162 p0 = __float22bfloat162_rn({f0.x, f0.y});
            __hip_bfloat162 p1 = __float22bfloat162_rn({f0.z, f0.w});
            __hip_bfloat162 p2 = __float22bfloat162_rn({f1.x, f1.y});
            __hip_bfloat162 p3 = __float22bfloat162_rn({f1.z, f1.w});
            af.u32[0] = *(unsigned*)&p0;
            af.u32[1] = *(unsigned*)&p1;
            af.u32[2] = *(unsigned*)&p2;
            af.u32[3] = *(unsigned*)&p3;
            acc0 = __builtin_amdgcn_mfma_f32_16x16x32_bf16(af.v, wf[ks * 2 + 0], acc0, 0, 0, 0);
            acc1 = __builtin_amdgcn_mfma_f32_16x16x32_bf16(af.v, wf[ks * 2 + 1], acc1, 0, 0, 0);
        }

        int f = m;
#pragma unroll
        for (int r = 0; r < 4; r++) {
            int l2 = tile * 16 + q * 4 + r;   // local row this lane writes
            int n2 = b * BNODES + l2;
            if (l2 < BNODES && n2 < NN) {
                float dv = dinvl[l2];
                hs[(size_t)n2 * HID + f]      = __float2bfloat16(dv * acc0[r]);
                hs[(size_t)n2 * HID + f + 16] = __float2bfloat16(dv * acc1[r]);
            }
        }
    }
}

// ---------------- fused: per-bucket gather + LDS counting sort + register pull + epilogue ----
__global__ __launch_bounds__(512) void k_agg(const int* __restrict__ offsT,
                                             const uint2* __restrict__ raw,
                                             const bf16* __restrict__ hs,
                                             const float* __restrict__ dinv,
                                             const float* __restrict__ b1, const float* __restrict__ W2,
                                             const float* __restrict__ b2, float* __restrict__ out) {
    __shared__ uint2 se[SSPAN];               // 37.9 KB (sorted records); aliased by runid in phase A
    __shared__ int P[PBLK + 1];               //  3.1 KB
    __shared__ int basearr[PBLK];             //  3.1 KB  (= O0[r] - P[r])
    __shared__ int hist[BNODES];
    __shared__ int scanbuf[BNODES];
    __shared__ int cur[BNODES];
    __shared__ int wt8[8];

    unsigned short* runid = (unsigned short*)se;   // dead before se is written

    int t = threadIdx.x;
    int b = blockIdx.x;
    if (t < BNODES) hist[t] = 0;

    // run lengths for this bucket across 768 partition blocks (2 per thread)
    int e0 = 2 * t, e1 = 2 * t + 1;
    int l0 = 0, l1 = 0, o0v = 0, o1v = 0;
    if (e0 < PBLK) {
        o0v = offsT[(size_t)b * PBLK + e0];
        l0  = offsT[(size_t)(b + 1) * PBLK + e0] - o0v;
    }
    if (e1 < PBLK) {
        o1v = offsT[(size_t)b * PBLK + e1];
        l1  = offsT[(size_t)(b + 1) * PBLK + e1] - o1v;
    }
    int psum = l0 + l1;
    int lane = t & 63;
    int incl = psum;
#pragma unroll
    for (int off = 1; off < 64; off <<= 1) {
        int up = __shfl_up(incl, off, 64);
        if (lane >= off) incl += up;
    }
    int wid = t >> 6;
    if (lane == 63) wt8[wid] = incl;
    __syncthreads();
    int woff = 0;
    for (int wj = 0; wj < wid; wj++) woff += wt8[wj];
    int exc = woff + incl - psum;
    if (e0 < PBLK) { P[e0] = exc;      basearr[e0] = o0v - exc; }
    if (e1 < PBLK) { P[e1] = exc + l0; basearr[e1] = o1v - (exc + l0); }
    if (t == 0) {
        int s = 0;
#pragma unroll
        for (int j = 0; j < 8; j++) s += wt8[j];
        P[PBLK] = s;
    }
    __syncthreads();

    int total = min(P[PBLK], SSPAN);

    // build d -> run map in the se region (short serial LDS fills, ~6 per run)
    for (int r = t; r < PBLK; r += 512) {
        int p0 = P[r], p1 = min(P[r + 1], SSPAN);
        for (int i = p0; i < p1; i++) runid[i] = (unsigned short)r;
    }
    __syncthreads();

    // pass 1: coalesced gather into REGISTERS + node histogram (<=10 recs/thread)
    uint2 rr[10];
#pragma unroll
    for (int k = 0; k < 10; k++) {
        int d = t + k * 512;
        if (d < total) {
            int r = runid[d];
            uint2 rec = raw[(size_t)r * EPB + (basearr[r] + d)];
            rr[k] = rec;
            int dl = (rec.x >> 20) & 255;
            atomicAdd(&hist[dl], 1);
        }
    }
    __syncthreads();   // runid dead from here; se region reusable

    // inclusive scan of node hist (Hillis-Steele over 131)
    if (t < BNODES) scanbuf[t] = hist[t];
    __syncthreads();
    for (int off = 1; off < BNODES; off <<= 1) {
        int v = 0;
        if (t < BNODES && t >= off) v = scanbuf[t - off];
        __syncthreads();
        if (t < BNODES) scanbuf[t] += v;
        __syncthreads();
    }
    if (t < BNODES) cur[t] = scanbuf[t] - hist[t];   // exclusive start
    __syncthreads();

    // pass 2: scatter from registers into se at final sorted positions
#pragma unroll
    for (int k = 0; k < 10; k++) {
        int d = t + k * 512;
        if (d < total) {
            uint2 rec = rr[k];
            int dl = (rec.x >> 20) & 255;
            int pos = atomicAdd(&cur[dl], 1);   // LDS int atomic
            se[pos] = make_uint2(rec.x & 0xFFFFF, rec.y);
        }
    }
    __syncthreads();

    // ---- phase B: per-group pull, register accumulate, fused epilogue ----
    // Full 8-blocks are unclamped (no cndmask chains); at most ONE clamped tail block.
    int gid = t >> 4;          // 0..31, 16 lanes each
    int l = t & 15;
    const __hip_bfloat162* hs2 = (const __hip_bfloat162*)hs;  // row stride 16
    for (int dl = gid; dl < BNODES; dl += 32) {
        int cnt = hist[dl];
        int rs = scanbuf[dl] - cnt;
        float a0 = 0.f, a1 = 0.f;
        int full = cnt & ~7;
        int bse = 0;
        for (; bse < full; bse += 8) {
            uint2 q0 = se[rs + bse + 0];
            uint2 q1 = se[rs + bse + 1];
            uint2 q2 = se[rs + bse + 2];
            uint2 q3 = se[rs + bse + 3];
            uint2 q4 = se[rs + bse + 4];
            uint2 q5 = se[rs + bse + 5];
            uint2 q6 = se[rs + bse + 6];
            uint2 q7 = se[rs + bse + 7];
            __hip_bfloat162 h0 = hs2[(size_t)q0.x * 16 + l];
            __hip_bfloat162 h1 = hs2[(size_t)q1.x * 16 + l];
            __hip_bfloat162 h2 = hs2[(size_t)q2.x * 16 + l];
            __hip_bfloat162 h3 = hs2[(size_t)q3.x * 16 + l];
            __hip_bfloat162 h4 = hs2[(size_t)q4.x * 16 + l];
            __hip_bfloat162 h5 = hs2[(size_t)q5.x * 16 + l];
            __hip_bfloat162 h6 = hs2[(size_t)q6.x * 16 + l];
            __hip_bfloat162 h7 = hs2[(size_t)q7.x * 16 + l];
            float2 f0 = __bfloat1622float2(h0); a0 += __uint_as_float(q0.y) * f0.x; a1 += __uint_as_float(q0.y) * f0.y;
            float2 f1 = __bfloat1622float2(h1); a0 += __uint_as_float(q1.y) * f1.x; a1 += __uint_as_float(q1.y) * f1.y;
            float2 f2 = __bfloat1622float2(h2); a0 += __uint_as_float(q2.y) * f2.x; a1 += __uint_as_float(q2.y) * f2.y;
            float2 f3 = __bfloat1622float2(h3); a0 += __uint_as_float(q3.y) * f3.x; a1 += __uint_as_float(q3.y) * f3.y;
            float2 f4 = __bfloat1622float2(h4); a0 += __uint_as_float(q4.y) * f4.x; a1 += __uint_as_float(q4.y) * f4.y;
            float2 f5 = __bfloat1622float2(h5); a0 += __uint_as_float(q5.y) * f5.x; a1 += __uint_as_float(q5.y) * f5.y;
            float2 f6 = __bfloat1622float2(h6); a0 += __uint_as_float(q6.y) * f6.x; a1 += __uint_as_float(q6.y) * f6.y;
            float2 f7 = __bfloat1622float2(h7); a0 += __uint_as_float(q7.y) * f7.x; a1 += __uint_as_float(q7.y) * f7.y;
        }
        if (bse < cnt) {
            int rem = cnt - bse;   // 1..7
            uint2 q0 = se[rs + bse];
            uint2 q1 = se[rs + bse + (rem > 1 ? 1 : 0)];
            uint2 q2 = se[rs + bse + (rem > 2 ? 2 : 0)];
            uint2 q3 = se[rs + bse + (rem > 3 ? 3 : 0)];
            uint2 q4 = se[rs + bse + (rem > 4 ? 4 : 0)];
            uint2 q5 = se[rs + bse + (rem > 5 ? 5 : 0)];
            uint2 q6 = se[rs + bse + (rem > 6 ? 6 : 0)];
            float w0 = __uint_as_float(q0.y);
            float w1 = rem > 1 ? __uint_as_float(q1.y) : 0.f;
            float w2 = rem > 2 ? __uint_as_float(q2.y) : 0.f;
            float w3 = rem > 3 ? __uint_as_float(q3.y) : 0.f;
            float w4 = rem > 4 ? __uint_as_float(q4.y) : 0.f;
            float w5 = rem > 5 ? __uint_as_float(q5.y) : 0.f;
            float w6 = rem > 6 ? __uint_as_float(q6.y) : 0.f;
            __hip_bfloat162 h0 = hs2[(size_t)q0.x * 16 + l];
            __hip_bfloat162 h1 = hs2[(size_t)q1.x * 16 + l];
            __hip_bfloat162 h2 = hs2[(size_t)q2.x * 16 + l];
            __hip_bfloat162 h3 = hs2[(size_t)q3.x * 16 + l];
            __hip_bfloat162 h4 = hs2[(size_t)q4.x * 16 + l];
            __hip_bfloat162 h5 = hs2[(size_t)q5.x * 16 + l];
            __hip_bfloat162 h6 = hs2[(size_t)q6.x * 16 + l];
            float2 f0 = __bfloat1622float2(h0); a0 += w0 * f0.x; a1 += w0 * f0.y;
            float2 f1 = __bfloat1622float2(h1); a0 += w1 * f1.x; a1 += w1 * f1.y;
            float2 f2 = __bfloat1622float2(h2); a0 += w2 * f2.x; a1 += w2 * f2.y;
            float2 f3 = __bfloat1622float2(h3); a0 += w3 * f3.x; a1 += w3 * f3.y;
            float2 f4 = __bfloat1622float2(h4); a0 += w4 * f4.x; a1 += w4 * f4.y;
            float2 f5 = __bfloat1622float2(h5); a0 += w5 * f5.x; a1 += w5 * f5.y;
            float2 f6 = __bfloat1622float2(h6); a0 += w6 * f6.x; a1 += w6 * f6.y;
        }
        int node = b * BNODES + dl;
        if (node < NN) {
            float dv = dinv[node];
            float2 fs = __bfloat1622float2(hs2[(size_t)node * 16 + l]);
            float v0 = dv * (a0 + fs.x) + b1[2 * l];
            float v1 = dv * (a1 + fs.y) + b1[2 * l + 1];
            v0 = fmaxf(v0, 0.f);
            v1 = fmaxf(v1, 0.f);
            float ps = v0 * W2[2 * l] + v1 * W2[2 * l + 1];
#pragma unroll
            for (int m2 = 8; m2 >= 1; m2 >>= 1) ps += __shfl_xor(ps, m2, 16);
            if (l == 0) out[node] = ps + b2[0];
        }
    }
}

// ---------------- launch ----------------
extern "C" void kernel_launch(void* const* d_in, const int* in_sizes, int n_in,
                              void* d_out, int out_size, void* d_ws, size_t ws_size,
                              hipStream_t stream) {
    const float* x  = (const float*)d_in[0];
    const int*   ei = (const int*)d_in[1];
    const float* ew = (const float*)d_in[2];
    const float* W1 = (const float*)d_in[3];
    const float* b1 = (const float*)d_in[4];
    const float* W2 = (const float*)d_in[5];
    const float* b2 = (const float*)d_in[6];
    float* out = (float*)d_out;

    char* ws = (char*)d_ws;
    // ws layout (bytes), total ~37.1 MB.
    uint2* raw   = (uint2*)(ws + 0);           // PBLK*EPB uint2 = 25,608,192
    int*   offs  = (int*)  (ws + 25608192);    // PBLK*NBP1 int = 2,350,080 -> 27,958,272
    int*   offsT = (int*)  (ws + 27958272);    // NBP1*PBLK int = 2,350,080 -> 30,308,352
    bf16*  hs    = (bf16*) (ws + 30308352);    // NN*HID bf16 = 6,400,000 -> 36,708,352
    float* dinv  = (float*)(ws + 36708352);    // NN floats -> 37,108,352

    k_part<<<PBLK, 512, 0, stream>>>(ei, ew, offs, raw);
    k_trans<<<dim3((NBP1 + 31) / 32, (PBLK + 31) / 32), 256, 0, stream>>>(offs, offsT);
    k_dh<<<NB, 512, 0, stream>>>(offsT, raw, x, W1, dinv, hs);
    k_agg<<<NB, 512, 0, stream>>>(offsT, raw, hs, dinv, b1, W2, b2, out);
}